// Round 1
// baseline (258.171 us; speedup 1.0000x reference)
//
#include <hip/hip_runtime.h>
#include <math.h>

#define BB 8
#define NN 2048
#define FF 64

// ---------------------------------------------------------------------------
// K1: Wh = h @ W  (B*N x 64) ; f1 = Wh@a1 ; f2 = Wh@a2
// block = 256 threads = 4 rows x 64 features; each wave owns one row.
// ---------------------------------------------------------------------------
__global__ __launch_bounds__(256) void k1_gemm(const float* __restrict__ h,
                                               const float* __restrict__ W,
                                               const float* __restrict__ a,
                                               float* __restrict__ Wh,
                                               float* __restrict__ f1,
                                               float* __restrict__ f2) {
  __shared__ float Wl[FF * FF];
  __shared__ float hl[4 * FF];
  __shared__ float a1l[FF], a2l[FF];
  const int tid = threadIdx.x;
  const int r = tid >> 6, f = tid & 63;
  for (int i = tid; i < FF * FF; i += 256) Wl[i] = W[i];
  if (tid < FF) { a1l[tid] = a[tid]; a2l[tid] = a[FF + tid]; }
  const int row0 = blockIdx.x * 4;
  for (int i = tid; i < 4 * FF; i += 256) hl[i] = h[(size_t)row0 * FF + i];
  __syncthreads();
  const int row = row0 + r;
  float acc = 0.f;
#pragma unroll
  for (int k = 0; k < FF; ++k) acc = fmaf(hl[r * FF + k], Wl[k * FF + f], acc);
  Wh[(size_t)row * FF + f] = acc;
  float v1 = acc * a1l[f];
  float v2 = acc * a2l[f];
#pragma unroll
  for (int o = 32; o > 0; o >>= 1) {
    v1 += __shfl_xor(v1, o, 64);
    v2 += __shfl_xor(v2, o, 64);
  }
  if (f == 0) { f1[row] = v1; f2[row] = v2; }
}

// ---------------------------------------------------------------------------
// K2: per-batch bitonic sort of (f2, index) ascending. One block per batch.
// ---------------------------------------------------------------------------
__global__ __launch_bounds__(1024) void k2_sort(const float* __restrict__ f2,
                                                float* __restrict__ f2s,
                                                int* __restrict__ idxs) {
  __shared__ float key[NN];
  __shared__ int val[NN];
  const int b = blockIdx.x, tid = threadIdx.x;
  for (int i = tid; i < NN; i += 1024) { key[i] = f2[b * NN + i]; val[i] = i; }
  __syncthreads();
  for (int k = 2; k <= NN; k <<= 1) {
    for (int j = k >> 1; j > 0; j >>= 1) {
      for (int i = tid; i < NN; i += 1024) {
        const int ixj = i ^ j;
        if (ixj > i) {
          const bool up = ((i & k) == 0);
          const float ki = key[i], kj = key[ixj];
          if ((ki > kj) == up) {
            key[i] = kj; key[ixj] = ki;
            const int vi = val[i]; val[i] = val[ixj]; val[ixj] = vi;
          }
        }
      }
      __syncthreads();
    }
  }
  for (int i = tid; i < NN; i += 1024) {
    f2s[b * NN + i] = key[i];
    idxs[b * NN + i] = val[i];
  }
}

// ---------------------------------------------------------------------------
// K3: per (batch, feature-or-scalar) scans over sorted order, double accum.
//   P_lo[b][p][f] = sum_{q<p}  e^{0.01*f2s_q} * Wh[idx_q][f]   (p in [0..N])
//   S_hi[b][p][f] = sum_{q>=p} e^{f2s_q}      * Wh[idx_q][f]   (p in [0..N])
// blockIdx.x in [0..64]; 64 => scalar (val=1) into Pz/Sz. blockIdx.y = batch.
// 256 threads x 8 elements each.
// ---------------------------------------------------------------------------
__global__ __launch_bounds__(256) void k3_scan(const float* __restrict__ Wh,
                                               const float* __restrict__ f2s,
                                               const int* __restrict__ idxs,
                                               float* __restrict__ S_hi,
                                               float* __restrict__ P_lo,
                                               float* __restrict__ Sz,
                                               float* __restrict__ Pz) {
  __shared__ double sl[256];
  const int fi = blockIdx.x;  // 0..64
  const int b = blockIdx.y;
  const int t = threadIdx.x;
  const float* f2b = f2s + (size_t)b * NN;
  const int* idb = idxs + (size_t)b * NN;

  // ---- pass A: exclusive prefix with lo weights (ascending) ----
  {
    double v[8]; double s = 0.0;
#pragma unroll
    for (int i = 0; i < 8; ++i) {
      const int q = t * 8 + i;
      const double w = exp(0.01 * (double)f2b[q]);
      const double vv = (fi < FF) ? (double)Wh[((size_t)b * NN + idb[q]) * FF + fi] : 1.0;
      v[i] = w * vv; s += v[i];
    }
    sl[t] = s; __syncthreads();
    for (int off = 1; off < 256; off <<= 1) {
      const double add = (t >= off) ? sl[t - off] : 0.0;
      __syncthreads();
      sl[t] += add;
      __syncthreads();
    }
    double run = (t > 0) ? sl[t - 1] : 0.0;
    const double tot = sl[255];
#pragma unroll
    for (int i = 0; i < 8; ++i) {
      const int q = t * 8 + i;
      if (fi < FF) P_lo[((size_t)b * (NN + 1) + q) * FF + fi] = (float)run;
      else         Pz[(size_t)b * (NN + 1) + q] = (float)run;
      run += v[i];
    }
    if (t == 255) {
      if (fi < FF) P_lo[((size_t)b * (NN + 1) + NN) * FF + fi] = (float)tot;
      else         Pz[(size_t)b * (NN + 1) + NN] = (float)tot;
    }
    __syncthreads();
  }

  // ---- pass B: inclusive suffix with hi weights (reversed order) ----
  {
    double v[8]; double s = 0.0;
#pragma unroll
    for (int i = 0; i < 8; ++i) {
      const int q = NN - 1 - (t * 8 + i);
      const double w = exp((double)f2b[q]);
      const double vv = (fi < FF) ? (double)Wh[((size_t)b * NN + idb[q]) * FF + fi] : 1.0;
      v[i] = w * vv; s += v[i];
    }
    sl[t] = s; __syncthreads();
    for (int off = 1; off < 256; off <<= 1) {
      const double add = (t >= off) ? sl[t - off] : 0.0;
      __syncthreads();
      sl[t] += add;
      __syncthreads();
    }
    double run = (t > 0) ? sl[t - 1] : 0.0;
#pragma unroll
    for (int i = 0; i < 8; ++i) {
      const int q = NN - 1 - (t * 8 + i);
      const double inc = run + v[i];  // S_hi[q] = sum_{q' >= q}
      if (fi < FF) S_hi[((size_t)b * (NN + 1) + q) * FF + fi] = (float)inc;
      else         Sz[(size_t)b * (NN + 1) + q] = (float)inc;
      run = inc;
    }
    if (t == 0) {
      if (fi < FF) S_hi[((size_t)b * (NN + 1) + NN) * FF + fi] = 0.f;
      else         Sz[(size_t)b * (NN + 1) + NN] = 0.f;
    }
  }
}

// ---------------------------------------------------------------------------
// K4: per row binary-search split point, combine. 4 rows x 64 feats / block.
// ---------------------------------------------------------------------------
__global__ __launch_bounds__(256) void k4_out(const float* __restrict__ f1,
                                              const float* __restrict__ f2s,
                                              const float* __restrict__ S_hi,
                                              const float* __restrict__ P_lo,
                                              const float* __restrict__ Sz,
                                              const float* __restrict__ Pz,
                                              float* __restrict__ out) {
  const int tid = threadIdx.x;
  const int r = tid >> 6, f = tid & 63;
  const int row = blockIdx.x * 4 + r;
  const int b = row >> 11;  // N = 2048
  const float* f2b = f2s + (size_t)b * NN;
  const float f1v = f1[row];
  const float t = -f1v;
  int lo = 0, hi = NN;
  while (lo < hi) {
    const int mid = (lo + hi) >> 1;
    if (f2b[mid] < t) lo = mid + 1; else hi = mid;
  }
  const int p0 = lo;  // first sorted index with f2 >= -f1  (the "hi" set start)
  const double w1 = exp((double)f1v);
  const double w2 = exp(0.01 * (double)f1v);
  const size_t bp = (size_t)b * (NN + 1) + p0;
  const double num = w1 * (double)S_hi[bp * FF + f] + w2 * (double)P_lo[bp * FF + f];
  const double Z = w1 * (double)Sz[bp] + w2 * (double)Pz[bp];
  out[(size_t)row * FF + f] = (float)(num / Z);
}

extern "C" void kernel_launch(void* const* d_in, const int* in_sizes, int n_in,
                              void* d_out, int out_size, void* d_ws, size_t ws_size,
                              hipStream_t stream) {
  const float* h = (const float*)d_in[0];
  // d_in[1] = adj : unused by the reference (all-ones, never read)
  const float* W = (const float*)d_in[2];
  const float* a = (const float*)d_in[3];
  float* out = (float*)d_out;

  float* ws = (float*)d_ws;
  size_t o = 0;
  float* Wh  = ws + o; o += (size_t)BB * NN * FF;        // 1,048,576
  float* f1  = ws + o; o += (size_t)BB * NN;             // 16,384
  float* f2  = ws + o; o += (size_t)BB * NN;
  float* f2s = ws + o; o += (size_t)BB * NN;
  int*   idxs = (int*)(ws + o); o += (size_t)BB * NN;
  float* S_hi = ws + o; o += (size_t)BB * (NN + 1) * FF; // 1,049,088
  float* P_lo = ws + o; o += (size_t)BB * (NN + 1) * FF;
  float* Sz  = ws + o; o += (size_t)BB * (NN + 1);
  float* Pz  = ws + o; o += (size_t)BB * (NN + 1);

  k1_gemm<<<BB * NN / 4, 256, 0, stream>>>(h, W, a, Wh, f1, f2);
  k2_sort<<<BB, 1024, 0, stream>>>(f2, f2s, idxs);
  dim3 g3(FF + 1, BB);
  k3_scan<<<g3, 256, 0, stream>>>(Wh, f2s, idxs, S_hi, P_lo, Sz, Pz);
  k4_out<<<BB * NN / 4, 256, 0, stream>>>(f1, f2s, S_hi, P_lo, Sz, Pz, out);
}